// Round 7
// baseline (649.527 us; speedup 1.0000x reference)
//
#include <hip/hip_runtime.h>

// LSTMDecoder: B=4096, LATENT=128, SEQ=512, HID=32, OUT=64. f32 in/out.
// Round 14b: TWO INDEPENDENT BARRIER DOMAINS PER CU (H-convoy test, resubmit;
// r14 bench was an infra failure, kernel audited safe: bounded reads/stores,
// uniform barrier counts, finite garbage-lane arithmetic).
//
//  - Diagnosis r8-r13: per-step wall ~1140 cyc vs ~350 cyc itemized pipe work.
//    The block-wide barrier convoys all 8 waves into the same phase; read
//    latency (130), LDS pipe drain, transc burst (160/SIMD), write+lgkm+barrier
//    serialize as a SUM each step. One barrier domain per CU = nothing fills
//    the bubbles.
//  - FIX: ROWS=8, grid=512 -> 2 blocks/CU, independent barriers. Block B's
//    waves issue inside block A's latency bubbles and vice versa. Cost: lanes
//    n_>=8 process garbage rows (transc issue/SIMD doubles to ~320 cyc; floor
//    68 us). Predicted net win if convoy-limited (H-convoy).
//  - Per-block structure = r11 EXACTLY (best so far, 583.5): fused single gate
//    MFMA (permuted Atil, scale-folded -log2e/+2log2e), padded hx (20 B rows,
//    2-way banks), 1 lgkm barrier/step, 4x conflict-free b32 rebuild, proj
//    hoisted above gate MFMA (y deferred 1 step), balanced jj==par proj.
//  - Safety: z row index clamped (garbage rows get finite real h0; no NaN:
//    rcp(Inf)=0 keeps h finite). y-stores predicated on n_ < 8.
//  - __launch_bounds__(512,4): force VGPR<=128 so 2 blocks/CU co-reside.

#define B_SZ   4096
#define LATENT 128
#define SEQ    512
#define HID    32
#define OUT_N  64
#define ROWS   8    // rows per block (16-col MFMA tile half-used)
#define LSW    40   // h0 staging row stride in halves (80 B rows)
#define HXW    10   // hx row stride in halves (20 B rows)

typedef _Float16 f16x8 __attribute__((ext_vector_type(8)));
typedef _Float16 f16x4 __attribute__((ext_vector_type(4)));
typedef float    f32x4 __attribute__((ext_vector_type(4)));

__device__ __forceinline__ float fexp2(float x) { return __builtin_amdgcn_exp2f(x); }
__device__ __forceinline__ float frcp(float x)  { return __builtin_amdgcn_rcpf(x); }
__device__ __forceinline__ void lds_barrier() {
    asm volatile("s_waitcnt lgkmcnt(0)\n\ts_barrier" ::: "memory");
}

__global__ __launch_bounds__(512, 4)
void lstm_db14(const float* __restrict__ z,
               const float* __restrict__ init_W,
               const float* __restrict__ init_b,
               const float* __restrict__ W_hh,
               const float* __restrict__ b_ih,
               const float* __restrict__ b_hh,
               const float* __restrict__ out_W,
               const float* __restrict__ out_b,
               float* __restrict__ y)
{
    __shared__ __align__(16) _Float16 hst[16 * LSW];
    __shared__ __align__(4) unsigned short hx[2][64][HXW];

    const int tid  = threadIdx.x;
    const int w    = tid >> 6;          // wave 0..7
    const int lane = tid & 63;
    const int n_   = lane & 15;         // batch row within tile (MFMA col)
    const int kb   = lane >> 4;         // k-group / quad group
    const int jj   = w & 1;             // cell half
    const int r_   = w >> 1;            // cell sub-index this wave activates (0..3)
    const int rbase = blockIdx.x * ROWS;

    const float NL2E  = -1.44269504088896341f;   // -log2(e)
    const float P2L2E =  2.88539008177792681f;   // +2*log2(e)

    // ---- fused gate A-frag: Atil row d = W_hh row 32*(d&3)+16jj+4*(d>>2)+r_ ----
    f16x8 wf1;
    f32x4 bacc1;
    {
        const int arow = 32 * (n_ & 3) + 16 * jj + 4 * (n_ >> 2) + r_;
        const float asc = ((n_ & 3) == 2) ? P2L2E : NL2E;
        const float* wrow = W_hh + (size_t)arow * HID;
#pragma unroll
        for (int rr = 0; rr < 4; rr++) {
            wf1[rr]     = (_Float16)(asc * wrow[4 * kb + rr]);
            wf1[4 + rr] = (_Float16)(asc * wrow[16 + 4 * kb + rr]);
        }
#pragma unroll
        for (int r = 0; r < 4; r++) {
            const int G = 32 * r + 16 * jj + 4 * kb + r_;
            const float bsc = (r == 2) ? P2L2E : NL2E;
            bacc1[r] = bsc * (b_ih[G] + b_hh[G]);
        }
    }

    // ---- proj A-frag (each wave owns tile p=r_; both jj groups keep a copy) ----
    f16x8 owf;
    f32x4 oacc;
    {
        const int p = r_;
        const float* row = out_W + (size_t)(16 * p + n_) * HID;
#pragma unroll
        for (int rr = 0; rr < 4; rr++) {
            owf[rr]     = (_Float16)row[4 * kb + rr];
            owf[4 + rr] = (_Float16)row[4 * kb + 16 + rr];
        }
#pragma unroll
        for (int r = 0; r < 4; r++) oacc[r] = out_b[16 * p + 4 * kb + r];
    }

    // ---- h0 = z @ init_W^T + init_b; stage 16 rows (rows >= ROWS clamped) ----
    {
        int m = tid >> 5, j = tid & 31;
        int zr = rbase + m;
        if (zr > B_SZ - 1) zr = B_SZ - 1;        // finite garbage for n_>=ROWS
        const float4* zp = (const float4*)(z + (size_t)zr * LATENT);
        const float4* wp = (const float4*)(init_W + (size_t)j * LATENT);
        float acc = init_b[j];
#pragma unroll
        for (int k = 0; k < LATENT / 4; k++) {
            float4 a4 = zp[k], b4 = wp[k];
            acc = fmaf(a4.x, b4.x, acc); acc = fmaf(a4.y, b4.y, acc);
            acc = fmaf(a4.z, b4.z, acc); acc = fmaf(a4.w, b4.w, acc);
        }
        hst[m * LSW + j] = (_Float16)acc;
    }
    __syncthreads();

    // initial fragment: slot 4jj'+rr <- h0[n_][4kb+rr / 16+4kb+rr]
    f16x8 a;
    {
        f16x4 lo = *(const f16x4*)&hst[n_ * LSW + 4 * kb];
        f16x4 hi = *(const f16x4*)&hst[n_ * LSW + 4 * kb + 16];
#pragma unroll
        for (int r = 0; r < 4; r++) { a[r] = lo[r]; a[4 + r] = hi[r]; }
    }

    float cs = 0.f;   // 2log2e-scaled cell state of cell 4kb+16jj+r_, row n_

    const bool vrow = (n_ < ROWS);      // this lane's batch row is real
    float* yb = y + (size_t)(rbase + n_) * SEQ * OUT_N + 16 * r_ + 4 * kb;

    for (int t = 0; t < SEQ; t += 4) {
#pragma unroll
        for (int u = 0; u < 4; u++) {
            const int par = u & 1;
            // ---- gate MFMA first: issues the moment the exchange read lands ----
            f32x4 acc = __builtin_amdgcn_mfma_f32_16x16x32_f16(wf1, a, bacc1, 0, 0, 0);

            // ---- deferred projection: a = h_s, store y[s-1] (group jj==par) ----
            if (jj == par) {
                f32x4 py = __builtin_amdgcn_mfma_f32_16x16x32_f16(owf, a, oacc, 0, 0, 0);
                if ((t + u) && vrow)
                    *(f32x4*)(yb + (size_t)(t + u - 1) * OUT_N) = py;
            }

            // ---- activation (scales pre-folded; cs = 2log2e * c) ----
            {
                float gi = frcp(1.f + fexp2(acc[0]));
                float gf = frcp(1.f + fexp2(acc[1]));
                float rg = frcp(1.f + fexp2(acc[2]));
                float go = frcp(1.f + fexp2(acc[3]));
                float g2 = fmaf(-2.f * P2L2E, rg, P2L2E);  // 2log2e * tanh(pre_g)
                float csn = fmaf(gf, cs, gi * g2);
                cs = csn;
                float rt = frcp(1.f + fexp2(csn));
                float hh = fmaf(-2.f * go, rt, go);        // go * tanh(c)
                union { _Float16 h; unsigned short u16; } cv;
                cv.h = (_Float16)hh;
                hx[par][lane][4 * jj + r_] = cv.u16;
            }
            lds_barrier();

            // ---- rebuild fragment: 4x ds_read_b32, conflict-free, slot order ----
            {
                union { unsigned u[4]; f16x8 v; } ua;
                const unsigned* rp = (const unsigned*)&hx[par][lane][0];
                ua.u[0] = rp[0]; ua.u[1] = rp[1]; ua.u[2] = rp[2]; ua.u[3] = rp[3];
                a = ua.v;
            }
        }
    }

    // ---- tail: y[511] = proj(h_512) (jj==0 group; par of step 512 is 0) ----
    if (jj == 0) {
        f32x4 py = __builtin_amdgcn_mfma_f32_16x16x32_f16(owf, a, oacc, 0, 0, 0);
        if (vrow) *(f32x4*)(yb + (size_t)(SEQ - 1) * OUT_N) = py;
    }
}

extern "C" void kernel_launch(void* const* d_in, const int* in_sizes, int n_in,
                              void* d_out, int out_size, void* d_ws, size_t ws_size,
                              hipStream_t stream) {
    const float* z      = (const float*)d_in[0];
    const float* init_W = (const float*)d_in[1];
    const float* init_b = (const float*)d_in[2];
    // d_in[3] = W_ih: unused (x input is all zeros; only biases survive)
    const float* W_hh   = (const float*)d_in[4];
    const float* b_ih   = (const float*)d_in[5];
    const float* b_hh   = (const float*)d_in[6];
    const float* out_W  = (const float*)d_in[7];
    const float* out_b  = (const float*)d_in[8];
    float* yout = (float*)d_out;

    lstm_db14<<<B_SZ / ROWS, 512, 0, stream>>>(z, init_W, init_b, W_hh, b_ih, b_hh,
                                               out_W, out_b, yout);
}

// Round 8
// 590.161 us; speedup vs baseline: 1.1006x; 1.1006x over previous
//
#include <hip/hip_runtime.h>

// LSTMDecoder: B=4096, LATENT=128, SEQ=512, HID=32, OUT=64. f32 in/out.
// Round 15: transc-count cut + proj-under-read-latency, on the r11 skeleton.
//
//  - LAW (r11/r12/r13/r14b fit): wall/step = transc_issue/SIMD (16 cyc/instr)
//    + ~820 cyc. Transc instrs convert 1:1 to wall; independent barrier
//    domains DON'T shrink the 820 (r14b falsified H-convoy). So: cut content.
//  - ACT: fused rcp for i*g: sig(i)*tanh(g) = (Eg-1)*rcp((1+Fi)(Eg+1));
//    10 -> 9 transc/cell. o*tanh(c) keeps the r11 saturating form (Ec can
//    overflow to Inf; rcp(Inf)=0 -> h=go, correct; fused form would NaN).
//  - PROJ SHADOW: exchange read moved to TOP of body; proj MFMA + store use
//    the OLD `a` (y lag = 2 steps) and issue between read-issue and the lgkm
//    wait -> ~40 cyc of work inside the ~130-cyc ds_read latency. Every wave
//    projects every step (tile p=r_), stores jj-split by row-half (n_>>3==jj)
//    so each y element is stored exactly once.
//  - Skeleton from r11 (583.5 best): fused single gate MFMA (permuted Atil,
//    scale-folded -log2e/+2log2e), padded hx (20 B rows, 2-way banks = free),
//    ONE lgkm barrier/step, 4x conflict-free b32 rebuild.
//  - Buffers: Body(tu) reads hx[tu&1] (top, after barrier), writes h_{tu+1}
//    to hx[(tu+1)&1]. h0 pre-seeded into hx[0] before the loop.

#define B_SZ   4096
#define LATENT 128
#define SEQ    512
#define HID    32
#define OUT_N  64
#define ROWS   16
#define LSW    40   // h0 staging row stride in halves (80 B rows)
#define HXW    10   // hx row stride in halves (20 B rows)

typedef _Float16 f16x8 __attribute__((ext_vector_type(8)));
typedef _Float16 f16x4 __attribute__((ext_vector_type(4)));
typedef float    f32x4 __attribute__((ext_vector_type(4)));

__device__ __forceinline__ float fexp2(float x) { return __builtin_amdgcn_exp2f(x); }
__device__ __forceinline__ float frcp(float x)  { return __builtin_amdgcn_rcpf(x); }
__device__ __forceinline__ void lds_barrier() {
    asm volatile("s_waitcnt lgkmcnt(0)\n\ts_barrier" ::: "memory");
}

__global__ __launch_bounds__(512)
void lstm_sp15(const float* __restrict__ z,
               const float* __restrict__ init_W,
               const float* __restrict__ init_b,
               const float* __restrict__ W_hh,
               const float* __restrict__ b_ih,
               const float* __restrict__ b_hh,
               const float* __restrict__ out_W,
               const float* __restrict__ out_b,
               float* __restrict__ y)
{
    __shared__ __align__(16) _Float16 hst[ROWS * LSW];
    __shared__ __align__(4) unsigned short hx[2][64][HXW];

    const int tid  = threadIdx.x;
    const int w    = tid >> 6;          // wave 0..7
    const int lane = tid & 63;
    const int n_   = lane & 15;         // batch row within tile (MFMA col)
    const int kb   = lane >> 4;         // k-group / quad group
    const int jj   = w & 1;             // cell half
    const int r_   = w >> 1;            // cell sub-index this wave activates (0..3)
    const int rbase = blockIdx.x * ROWS;

    const float NL2E  = -1.44269504088896341f;   // -log2(e)
    const float P2L2E =  2.88539008177792681f;   // +2*log2(e)

    // ---- fused gate A-frag: Atil row d = W_hh row 32*(d&3)+16jj+4*(d>>2)+r_ ----
    f16x8 wf1;
    f32x4 bacc1;
    {
        const int arow = 32 * (n_ & 3) + 16 * jj + 4 * (n_ >> 2) + r_;
        const float asc = ((n_ & 3) == 2) ? P2L2E : NL2E;
        const float* wrow = W_hh + (size_t)arow * HID;
#pragma unroll
        for (int rr = 0; rr < 4; rr++) {
            wf1[rr]     = (_Float16)(asc * wrow[4 * kb + rr]);
            wf1[4 + rr] = (_Float16)(asc * wrow[16 + 4 * kb + rr]);
        }
#pragma unroll
        for (int r = 0; r < 4; r++) {
            const int G = 32 * r + 16 * jj + 4 * kb + r_;
            const float bsc = (r == 2) ? P2L2E : NL2E;
            bacc1[r] = bsc * (b_ih[G] + b_hh[G]);
        }
    }

    // ---- proj A-frag: every wave owns tile p=r_ ----
    f16x8 owf;
    f32x4 oacc;
    {
        const int p = r_;
        const float* row = out_W + (size_t)(16 * p + n_) * HID;
#pragma unroll
        for (int rr = 0; rr < 4; rr++) {
            owf[rr]     = (_Float16)row[4 * kb + rr];
            owf[4 + rr] = (_Float16)row[4 * kb + 16 + rr];
        }
#pragma unroll
        for (int r = 0; r < 4; r++) oacc[r] = out_b[16 * p + 4 * kb + r];
    }

    // ---- h0 = z @ init_W^T + init_b (one cell per thread: 512 = 16x32) ----
    {
        int m = tid >> 5, j = tid & 31;
        const float4* zp = (const float4*)(z + (size_t)(rbase + m) * LATENT);
        const float4* wp = (const float4*)(init_W + (size_t)j * LATENT);
        float acc = init_b[j];
#pragma unroll
        for (int k = 0; k < LATENT / 4; k++) {
            float4 a4 = zp[k], b4 = wp[k];
            acc = fmaf(a4.x, b4.x, acc); acc = fmaf(a4.y, b4.y, acc);
            acc = fmaf(a4.z, b4.z, acc); acc = fmaf(a4.w, b4.w, acc);
        }
        hst[m * LSW + j] = (_Float16)acc;
    }
    __syncthreads();

    // ---- seed h0 into exchange layout: wave's own cell -> hx[0][lane][slot] ----
    {
        union { _Float16 h; unsigned short u16; } cv;
        cv.h = hst[n_ * LSW + 4 * kb + 16 * jj + r_];
        hx[0][lane][4 * jj + r_] = cv.u16;
    }
    __syncthreads();

    f16x8 a;                            // h_{tu-1} at body top (proj operand)
#pragma unroll
    for (int r = 0; r < 8; r++) a[r] = (_Float16)0.f;

    float cs = 0.f;   // 2log2e-scaled cell state of cell 4kb+16jj+r_, row n_
    const bool vst = ((n_ >> 3) == jj); // this wave stores this lane's row-half

    float* yb = y + (size_t)(rbase + n_) * SEQ * OUT_N + 16 * r_ + 4 * kb;

    for (int t = 0; t < SEQ; t += 4) {
#pragma unroll
        for (int u = 0; u < 4; u++) {
            const int tu = t + u;
            lds_barrier();

            // ---- issue exchange reads of h_tu (no wait yet) ----
            const unsigned* rp = (const unsigned*)&hx[u & 1][lane][0];
            unsigned t0 = rp[0], t1 = rp[1], t2 = rp[2], t3 = rp[3];

            // ---- proj on OLD a = h_{tu-1} -> y[tu-2], in the read shadow ----
            {
                f32x4 py = __builtin_amdgcn_mfma_f32_16x16x32_f16(owf, a, oacc, 0, 0, 0);
                if (vst && tu >= 2)
                    *(f32x4*)(yb + (size_t)(tu - 2) * OUT_N) = py;
            }

            // ---- consume reads: a = h_tu (lgkm wait lands here) ----
            {
                union { unsigned u4[4]; f16x8 v; } ua;
                ua.u4[0] = t0; ua.u4[1] = t1; ua.u4[2] = t2; ua.u4[3] = t3;
                a = ua.v;
            }

            // ---- gate MFMA: regs 0..3 = scaled (i,f,g,o) pre-acts ----
            f32x4 acc = __builtin_amdgcn_mfma_f32_16x16x32_f16(wf1, a, bacc1, 0, 0, 0);

            // ---- activation: 9 transc (fused i*g rcp; saturating o*tanh(c)) ----
            {
                float Fi  = fexp2(acc[0]);                  // e^{-pre_i}
                float Eg  = fexp2(acc[2]);                  // e^{2 pre_g}
                float den = (1.f + Fi) * (1.f + Eg);
                float rig = frcp(den);
                float tg  = fmaf(P2L2E, Eg, -P2L2E);        // 2L*(Eg-1)
                float ig  = tg * rig;                       // 2L*sig(i)*tanh(g)
                float gf  = frcp(1.f + fexp2(acc[1]));
                float csn = fmaf(gf, cs, ig);
                cs = csn;
                float go  = frcp(1.f + fexp2(acc[3]));
                float rt  = frcp(1.f + fexp2(csn));         // rcp(1+e^{2c})
                float hh  = fmaf(-2.f * go, rt, go);        // go*tanh(c), NaN-safe
                union { _Float16 h; unsigned short u16; } cv;
                cv.h = (_Float16)hh;
                hx[(u & 1) ^ 1][lane][4 * jj + r_] = cv.u16;  // h_{tu+1}
            }
        }
    }

    // ---- tail: y[510] = proj(h_511) (a = h_511 here) ----
    {
        f32x4 py = __builtin_amdgcn_mfma_f32_16x16x32_f16(owf, a, oacc, 0, 0, 0);
        if (vst) *(f32x4*)(yb + (size_t)(SEQ - 2) * OUT_N) = py;
    }
    lds_barrier();
    // ---- y[511] = proj(h_512) from hx[0] (written by body tu=511) ----
    {
        union { unsigned u4[4]; f16x8 v; } ua;
        const unsigned* rp = (const unsigned*)&hx[0][lane][0];
        ua.u4[0] = rp[0]; ua.u4[1] = rp[1]; ua.u4[2] = rp[2]; ua.u4[3] = rp[3];
        a = ua.v;
        f32x4 py = __builtin_amdgcn_mfma_f32_16x16x32_f16(owf, a, oacc, 0, 0, 0);
        if (vst) *(f32x4*)(yb + (size_t)(SEQ - 1) * OUT_N) = py;
    }
}

extern "C" void kernel_launch(void* const* d_in, const int* in_sizes, int n_in,
                              void* d_out, int out_size, void* d_ws, size_t ws_size,
                              hipStream_t stream) {
    const float* z      = (const float*)d_in[0];
    const float* init_W = (const float*)d_in[1];
    const float* init_b = (const float*)d_in[2];
    // d_in[3] = W_ih: unused (x input is all zeros; only biases survive)
    const float* W_hh   = (const float*)d_in[4];
    const float* b_ih   = (const float*)d_in[5];
    const float* b_hh   = (const float*)d_in[6];
    const float* out_W  = (const float*)d_in[7];
    const float* out_b  = (const float*)d_in[8];
    float* yout = (float*)d_out;

    lstm_sp15<<<B_SZ / ROWS, 512, 0, stream>>>(z, init_W, init_b, W_hh, b_ih, b_hh,
                                               out_W, out_b, yout);
}

// Round 9
// 578.312 us; speedup vs baseline: 1.1231x; 1.0205x over previous
//
#include <hip/hip_runtime.h>

// LSTMDecoder: B=4096, LATENT=128, SEQ=512, HID=32, OUT=64. f32 in/out.
// Round 16: r11 skeleton EXACTLY + 8-transc activation (single-variable test).
//
//  - LAW (r11-r15 fit): per-SIMD issue cycles convert ~1:1 to wall. r14b:
//    +320 cyc transc issue -> +310 wall. r15: -32 transc but +50 proj/store
//    issue -> +30 wall. So: cut issue, change ONE thing at a time.
//  - ACT (10 -> 8 transc/cell): fuse BOTH sigmoid*tanh pairs:
//      sig(i)*tanh(g) = (Eg-1)*rcp((1+Fi)(1+Eg))
//      sig(o)*tanh(c) = (Ecs-1)*rcp((1+Fo)(1+Ecs)), Ecs = exp2(min(cs,126))
//    The fmin clamp kills the Inf*0=NaN path (exp2 overflow only at c>44,
//    unreachable in practice, but clamp makes it safe). Underflow side is
//    exact: Ecs=0 -> hh=-sig(o) correct saturation.
//  - Per SIMD/step: -4 transc (-64 cyc) + 8 VALU (+16 cyc) => -48 cyc/step.
//  - Everything else = r11 (best, 583.5): fused single gate MFMA (permuted
//    Atil, scale-folded -log2e/+2log2e), padded hx (20 B rows, 2-way banks),
//    ONE lgkm barrier/step, 4x conflict-free b32 rebuild, proj hoisted above
//    gate MFMA (y deferred 1 step), balanced jj==par proj.

#define B_SZ   4096
#define LATENT 128
#define SEQ    512
#define HID    32
#define OUT_N  64
#define ROWS   16
#define LSW    40   // h0 staging row stride in halves (80 B rows)
#define HXW    10   // hx row stride in halves (20 B rows)

typedef _Float16 f16x8 __attribute__((ext_vector_type(8)));
typedef _Float16 f16x4 __attribute__((ext_vector_type(4)));
typedef float    f32x4 __attribute__((ext_vector_type(4)));

__device__ __forceinline__ float fexp2(float x) { return __builtin_amdgcn_exp2f(x); }
__device__ __forceinline__ float frcp(float x)  { return __builtin_amdgcn_rcpf(x); }
__device__ __forceinline__ void lds_barrier() {
    asm volatile("s_waitcnt lgkmcnt(0)\n\ts_barrier" ::: "memory");
}

__global__ __launch_bounds__(512)
void lstm_tr16(const float* __restrict__ z,
               const float* __restrict__ init_W,
               const float* __restrict__ init_b,
               const float* __restrict__ W_hh,
               const float* __restrict__ b_ih,
               const float* __restrict__ b_hh,
               const float* __restrict__ out_W,
               const float* __restrict__ out_b,
               float* __restrict__ y)
{
    __shared__ __align__(16) _Float16 hst[ROWS * LSW];
    __shared__ __align__(4) unsigned short hx[2][64][HXW];  // 20 B rows

    const int tid  = threadIdx.x;
    const int w    = tid >> 6;          // wave 0..7
    const int lane = tid & 63;
    const int n_   = lane & 15;         // batch row within tile
    const int kb   = lane >> 4;         // k-group / quad group
    const int jj   = w & 1;             // cell half
    const int r_   = w >> 1;            // cell sub-index this wave activates (0..3)
    const int rbase = blockIdx.x * ROWS;

    const float NL2E  = -1.44269504088896341f;   // -log2(e)
    const float P2L2E =  2.88539008177792681f;   // +2*log2(e)

    // ---- fused gate A-frag: Atil row d = W_hh row 32*(d&3)+16jj+4*(d>>2)+r_ ----
    f16x8 wf1;
    f32x4 bacc1;
    {
        const int arow = 32 * (n_ & 3) + 16 * jj + 4 * (n_ >> 2) + r_;
        const float asc = ((n_ & 3) == 2) ? P2L2E : NL2E;
        const float* wrow = W_hh + (size_t)arow * HID;
#pragma unroll
        for (int rr = 0; rr < 4; rr++) {
            wf1[rr]     = (_Float16)(asc * wrow[4 * kb + rr]);
            wf1[4 + rr] = (_Float16)(asc * wrow[16 + 4 * kb + rr]);
        }
#pragma unroll
        for (int r = 0; r < 4; r++) {
            const int G = 32 * r + 16 * jj + 4 * kb + r_;
            const float bsc = (r == 2) ? P2L2E : NL2E;
            bacc1[r] = bsc * (b_ih[G] + b_hh[G]);
        }
    }

    // ---- proj A-frag (each wave owns tile p=r_; both jj groups keep a copy) ----
    f16x8 owf;
    f32x4 oacc;
    {
        const int p = r_;
        const float* row = out_W + (size_t)(16 * p + n_) * HID;
#pragma unroll
        for (int rr = 0; rr < 4; rr++) {
            owf[rr]     = (_Float16)row[4 * kb + rr];
            owf[4 + rr] = (_Float16)row[4 * kb + 16 + rr];
        }
#pragma unroll
        for (int r = 0; r < 4; r++) oacc[r] = out_b[16 * p + 4 * kb + r];
    }

    // ---- h0 = z @ init_W^T + init_b (one cell per thread: 512 = 16x32) ----
    {
        int m = tid >> 5, j = tid & 31;
        const float4* zp = (const float4*)(z + (size_t)(rbase + m) * LATENT);
        const float4* wp = (const float4*)(init_W + (size_t)j * LATENT);
        float acc = init_b[j];
#pragma unroll
        for (int k = 0; k < LATENT / 4; k++) {
            float4 a4 = zp[k], b4 = wp[k];
            acc = fmaf(a4.x, b4.x, acc); acc = fmaf(a4.y, b4.y, acc);
            acc = fmaf(a4.z, b4.z, acc); acc = fmaf(a4.w, b4.w, acc);
        }
        hst[m * LSW + j] = (_Float16)acc;
    }
    __syncthreads();

    // initial fragment: slot 4jj'+rr <- h0[n_][4kb+rr / 16+4kb+rr]
    f16x8 a;
    {
        f16x4 lo = *(const f16x4*)&hst[n_ * LSW + 4 * kb];
        f16x4 hi = *(const f16x4*)&hst[n_ * LSW + 4 * kb + 16];
#pragma unroll
        for (int r = 0; r < 4; r++) { a[r] = lo[r]; a[4 + r] = hi[r]; }
    }

    float cs = 0.f;   // 2log2e-scaled cell state of cell 4kb+16jj+r_, row n_

    float* yb = y + (size_t)(rbase + n_) * SEQ * OUT_N + 16 * r_ + 4 * kb;

    for (int t = 0; t < SEQ; t += 4) {
#pragma unroll
        for (int u = 0; u < 4; u++) {
            const int par = u & 1;
            // ---- gate MFMA first: issues the moment the exchange read lands ----
            f32x4 acc = __builtin_amdgcn_mfma_f32_16x16x32_f16(wf1, a, bacc1, 0, 0, 0);

            // ---- deferred projection: a = h_s, store y[s-1] (group jj==par) ----
            if (jj == par) {
                f32x4 py = __builtin_amdgcn_mfma_f32_16x16x32_f16(owf, a, oacc, 0, 0, 0);
                if (t + u) *(f32x4*)(yb + (size_t)(t + u - 1) * OUT_N) = py;
            }

            // ---- activation: 8 transc (both sig*tanh pairs rcp-fused) ----
            {
                float Fi  = fexp2(acc[0]);                  // e^{-x_i}
                float Ff  = fexp2(acc[1]);                  // e^{-x_f}
                float Eg  = fexp2(acc[2]);                  // e^{2 x_g}
                float Fo  = fexp2(acc[3]);                  // e^{-x_o}
                float rig = frcp((1.f + Fi) * (1.f + Eg));
                float tg  = fmaf(P2L2E, Eg, -P2L2E);        // 2L*(Eg-1)
                float ig  = tg * rig;                       // 2L*sig(i)*tanh(g)
                float gf  = frcp(1.f + Ff);                 // sig(f)
                float csn = fmaf(gf, cs, ig);               // 2L-scaled c
                cs = csn;
                float Ecs = fexp2(fminf(csn, 126.f));       // e^{2c}, overflow-safe
                float rd  = frcp((1.f + Fo) * (1.f + Ecs));
                float hh  = (Ecs - 1.f) * rd;               // sig(o)*tanh(c)
                union { _Float16 h; unsigned short u16; } cv;
                cv.h = (_Float16)hh;
                hx[par][lane][4 * jj + r_] = cv.u16;
            }
            lds_barrier();

            // ---- rebuild fragment: 4x ds_read_b32, conflict-free, slot order ----
            {
                union { unsigned uu[4]; f16x8 v; } ua;
                const unsigned* rp = (const unsigned*)&hx[par][lane][0];
                ua.uu[0] = rp[0]; ua.uu[1] = rp[1]; ua.uu[2] = rp[2]; ua.uu[3] = rp[3];
                a = ua.v;
            }
        }
    }

    // ---- tail: y[511] = proj(h_512) (jj==0 group; par of step 512 is 0) ----
    if (jj == 0) {
        f32x4 py = __builtin_amdgcn_mfma_f32_16x16x32_f16(owf, a, oacc, 0, 0, 0);
        *(f32x4*)(yb + (size_t)(SEQ - 1) * OUT_N) = py;
    }
}

extern "C" void kernel_launch(void* const* d_in, const int* in_sizes, int n_in,
                              void* d_out, int out_size, void* d_ws, size_t ws_size,
                              hipStream_t stream) {
    const float* z      = (const float*)d_in[0];
    const float* init_W = (const float*)d_in[1];
    const float* init_b = (const float*)d_in[2];
    // d_in[3] = W_ih: unused (x input is all zeros; only biases survive)
    const float* W_hh   = (const float*)d_in[4];
    const float* b_ih   = (const float*)d_in[5];
    const float* b_hh   = (const float*)d_in[6];
    const float* out_W  = (const float*)d_in[7];
    const float* out_b  = (const float*)d_in[8];
    float* yout = (float*)d_out;

    lstm_tr16<<<B_SZ / ROWS, 512, 0, stream>>>(z, init_W, init_b, W_hh, b_ih, b_hh,
                                               out_W, out_b, yout);
}